// Round 1
// baseline (9.954 us; speedup 1.0000x reference)
//
#include <hip/hip_runtime.h>
#include <math.h>

#define EMBED 1024

__global__ __launch_bounds__(256) void lstm_step_kernel(
    const unsigned int* __restrict__ tok,     // low word of int64 token id
    const float* __restrict__ h_in,           // [EMBED]
    const float* __restrict__ c_in,           // [EMBED]
    const float* __restrict__ embed,          // [VOCAB, EMBED]
    const float* __restrict__ W_ih,           // [4*EMBED, EMBED]
    const float* __restrict__ W_hh,           // [4*EMBED, EMBED]
    const float* __restrict__ b_ih,           // [4*EMBED]
    const float* __restrict__ b_hh,           // [4*EMBED]
    float* __restrict__ out)                  // [2*EMBED]: h_new | c_new
{
    __shared__ float x_s[EMBED];
    __shared__ float h_s[EMBED];
    __shared__ float gate_s[4];

    const int tid = threadIdx.x;
    const int j   = blockIdx.x;               // output element 0..1023

    const unsigned int t = tok[0];
    const float* xrow = embed + (size_t)t * EMBED;

    // Stage x (embedded token row) and h into LDS: 256 threads x float4
    {
        float4 xv = ((const float4*)xrow)[tid];
        float4 hv = ((const float4*)h_in)[tid];
        ((float4*)x_s)[tid] = xv;
        ((float4*)h_s)[tid] = hv;
    }
    __syncthreads();

    const int w    = tid >> 6;                 // wave 0..3 -> gate i,f,g,o
    const int lane = tid & 63;
    const int row  = w * EMBED + j;            // gate row index in [0, 4096)

    const float4* wi  = (const float4*)(W_ih + (size_t)row * EMBED);
    const float4* wh  = (const float4*)(W_hh + (size_t)row * EMBED);
    const float4* xs4 = (const float4*)x_s;
    const float4* hs4 = (const float4*)h_s;

    float acc = 0.f;
    #pragma unroll
    for (int k = 0; k < 4; ++k) {
        const int idx = lane + k * 64;         // 0..255 float4s per row
        float4 a = wi[idx];
        float4 b = xs4[idx];
        acc += a.x * b.x + a.y * b.y + a.z * b.z + a.w * b.w;
        float4 cc = wh[idx];
        float4 d  = hs4[idx];
        acc += cc.x * d.x + cc.y * d.y + cc.z * d.z + cc.w * d.w;
    }

    // 64-lane wave reduction
    #pragma unroll
    for (int off = 32; off > 0; off >>= 1)
        acc += __shfl_down(acc, off);

    if (lane == 0)
        gate_s[w] = acc + b_ih[row] + b_hh[row];
    __syncthreads();

    if (tid == 0) {
        const float gi = gate_s[0];
        const float gf = gate_s[1];
        const float gg = gate_s[2];
        const float go = gate_s[3];
        const float i = 1.f / (1.f + expf(-gi));
        const float f = 1.f / (1.f + expf(-gf));
        const float g = tanhf(gg);
        const float o = 1.f / (1.f + expf(-go));
        const float c_new = f * c_in[j] + i * g;
        const float h_new = o * tanhf(c_new);
        out[j]         = h_new;   // h_new first (tuple order)
        out[EMBED + j] = c_new;   // then c_new
    }
}

extern "C" void kernel_launch(void* const* d_in, const int* in_sizes, int n_in,
                              void* d_out, int out_size, void* d_ws, size_t ws_size,
                              hipStream_t stream) {
    const unsigned int* tok  = (const unsigned int*)d_in[0]; // int64 low word (LE)
    const float* h_in  = (const float*)d_in[1];
    const float* c_in  = (const float*)d_in[2];
    const float* embed = (const float*)d_in[3];
    const float* W_ih  = (const float*)d_in[4];
    const float* W_hh  = (const float*)d_in[5];
    const float* b_ih  = (const float*)d_in[6];
    const float* b_hh  = (const float*)d_in[7];
    float* out = (float*)d_out;

    lstm_step_kernel<<<EMBED, 256, 0, stream>>>(
        tok, h_in, c_in, embed, W_ih, W_hh, b_ih, b_hh, out);
}